// Round 13
// baseline (228.664 us; speedup 1.0000x reference)
//
#include <hip/hip_runtime.h>

#define NN 100000
#define NE 1600000
#define NB 782          // ceil(NN/128) coarse buckets, 128 nodes each
#define CHUNK 4096
#define BCAP 2560       // padded bucket capacity (mean 2048, sigma ~45 -> 11 sigma)
#define LDP 136         // LDS row pitch in bf16 (128 + 8 pad -> 272B, 2-way free)

typedef __attribute__((ext_vector_type(8))) short bf16x8;
typedef __attribute__((ext_vector_type(4))) float f32x4;

static __device__ __forceinline__ unsigned short f2bf(float f) {
  unsigned int u = __float_as_uint(f);
  u += 0x7fff + ((u >> 16) & 1);       // round-to-nearest-even
  return (unsigned short)(u >> 16);
}

// One-time: wt[c][k] = bf16(W[k][c]) (c<64 -> W_l, c>=64 -> W_r) + bucket cursor init
__global__ void wprep_k(const float* __restrict__ wl, const float* __restrict__ wr,
                        unsigned short* __restrict__ wt, int* __restrict__ bcursor) {
  int i = blockIdx.x * 256 + threadIdx.x;     // 16384
  int c = i >> 7, k = i & 127;
  float v = (c < 64) ? wl[k * 64 + c] : wr[k * 64 + (c - 64)];
  wt[i] = f2bf(v);
  if (i < NB) bcursor[i * 16] = i * BCAP;     // padded-region base
}

// MFMA bf16 GEMM, 64-row tiles (1 wave = 1 16-row M-tile), LDS 17.4 KB ->
// ~9 blocks/CU, 1563 blocks. A staged in LDS (coalesced, r8-proven-needed);
// B direct from the 16 KB L1/L2-resident wt. Output hb all-bf16.
__global__ __launch_bounds__(256) void gemm_mfma(const float* __restrict__ feat,
                                                 const unsigned short* __restrict__ wt,
                                                 unsigned short* __restrict__ hb) {
  __shared__ unsigned short ldsA[64][LDP];    // feat tile, bf16 [row][k]
  const int tid = threadIdx.x;
  const int row0 = blockIdx.x * 64;

  for (int it = 0; it < 8; ++it) {            // 64 rows x 32 float4 lanes
    int r = it * 8 + (tid >> 5);
    int gr = row0 + r;
    int k4 = (tid & 31) * 4;
    float4 v = make_float4(0.f, 0.f, 0.f, 0.f);
    if (gr < NN) v = *reinterpret_cast<const float4*>(&feat[(size_t)gr * 128 + k4]);
    union { unsigned short s[4]; uint2 u; } pk;
    pk.s[0] = f2bf(v.x); pk.s[1] = f2bf(v.y); pk.s[2] = f2bf(v.z); pk.s[3] = f2bf(v.w);
    *reinterpret_cast<uint2*>(&ldsA[r][k4]) = pk.u;
  }
  __syncthreads();

  const int w  = tid >> 6;          // wave 0..3 owns rows w*16..w*16+15
  const int ln = tid & 63;
  const int lr = ln & 15;
  const int kb = (ln >> 4) * 8;     // k-octet within a 32-wide K-step

  f32x4 acc[8];
#pragma unroll
  for (int nt = 0; nt < 8; ++nt) acc[nt] = (f32x4){0.f, 0.f, 0.f, 0.f};

#pragma unroll
  for (int t = 0; t < 4; ++t) {
    const int ko = t * 32 + kb;
    bf16x8 af = *reinterpret_cast<const bf16x8*>(&ldsA[w * 16 + lr][ko]);
    bf16x8 bfr[8];
#pragma unroll
    for (int nt = 0; nt < 8; ++nt)
      bfr[nt] = *reinterpret_cast<const bf16x8*>(&wt[(size_t)(nt * 16 + lr) * 128 + ko]);
#pragma unroll
    for (int nt = 0; nt < 8; ++nt)
      acc[nt] = __builtin_amdgcn_mfma_f32_16x16x32_bf16(af, bfr[nt], acc[nt], 0, 0, 0);
  }

  {
    int rrel = w * 16 + (ln >> 4) * 4;
#pragma unroll
    for (int q = 0; q < 4; ++q) {
      int gr = row0 + rrel + q;
      if (gr < NN) {
#pragma unroll
        for (int nt = 0; nt < 8; ++nt)
          hb[(size_t)gr * 128 + nt * 16 + lr] = f2bf(acc[nt][q]);
      }
    }
  }
}

// Bucket-partition edges into fixed padded regions (bucket b owns
// [b*BCAP, (b+1)*BCAP)). 512 threads. LDS-staged writeout.
// rec = (src<<7)|tgt_local.
__global__ __launch_bounds__(512) void bscatter_k(const int* __restrict__ edge,
                                                  int* __restrict__ bcursor,
                                                  int* __restrict__ brec) {
  __shared__ int lcnt[NB];
  __shared__ int lstart[NB];
  __shared__ int gbase[NB];
  __shared__ int lcur[NB];
  __shared__ int srec[CHUNK];
  __shared__ unsigned short bid[CHUNK];
  __shared__ int sd[512];
  const int tid = threadIdx.x;
  const int base = blockIdx.x * CHUNK;
  const int lim = min(CHUNK, NE - base);

  for (int b = tid; b < NB; b += 512) { lcnt[b] = 0; lcur[b] = 0; }
  __syncthreads();
  for (int i = tid; i < lim; i += 512)
    atomicAdd(&lcnt[edge[NE + base + i] >> 7], 1);
  __syncthreads();

  int v[2]; int s = 0;
#pragma unroll
  for (int j = 0; j < 2; ++j) {
    int idx = tid * 2 + j;
    v[j] = (idx < NB) ? lcnt[idx] : 0;
    s += v[j];
  }
  sd[tid] = s;
  __syncthreads();
  for (int off = 1; off < 512; off <<= 1) {
    int t = (tid >= off) ? sd[tid - off] : 0;
    __syncthreads();
    sd[tid] += t;
    __syncthreads();
  }
  int run = sd[tid] - s;
#pragma unroll
  for (int j = 0; j < 2; ++j) {
    int idx = tid * 2 + j;
    if (idx < NB) lstart[idx] = run;
    run += v[j];
  }
  __syncthreads();

  for (int b = tid; b < NB; b += 512)
    if (lcnt[b] > 0) gbase[b] = atomicAdd(&bcursor[b * 16], lcnt[b]);
  __syncthreads();

  for (int i = tid; i < lim; i += 512) {
    int tg = edge[NE + base + i];
    int sr = edge[base + i];
    int b = tg >> 7;
    int r = atomicAdd(&lcur[b], 1);
    int slot = lstart[b] + r;
    srec[slot] = (sr << 7) | (tg & 127);
    bid[slot] = (unsigned short)b;
  }
  __syncthreads();

  for (int i = tid; i < lim; i += 512) {
    int b = bid[i];
    brec[gbase[b] + i - lstart[b]] = srec[i];
  }
}

// Node-level sort within each padded bucket; emits absolute (start,end) per node.
__global__ __launch_bounds__(512) void bsort_k(int* __restrict__ brec,
                                               const int* __restrict__ bcursor,
                                               int2* __restrict__ srange) {
  __shared__ int srec[BCAP];
  __shared__ int ncnt[128];
  __shared__ int nst[128];
  __shared__ int sd2[128];
  const int tid = threadIdx.x;
  const int b = blockIdx.x;
  const int s0 = b * BCAP;
  const int cnt = bcursor[b * 16] - s0;

  if (tid < 128) ncnt[tid] = 0;
  __syncthreads();
  for (int i = tid; i < cnt; i += 512) {
    int r = brec[s0 + i];
    srec[i] = r;
    atomicAdd(&ncnt[r & 127], 1);
  }
  __syncthreads();

  int val = (tid < 128) ? ncnt[tid] : 0;
  if (tid < 128) sd2[tid] = val;
  __syncthreads();
  for (int off = 1; off < 128; off <<= 1) {
    int t = 0;
    if (tid < 128 && tid >= off) t = sd2[tid - off];
    __syncthreads();
    if (tid < 128) sd2[tid] += t;
    __syncthreads();
  }
  if (tid < 128) {
    int st = sd2[tid] - val;
    nst[tid] = st;
    int nid = (b << 7) + tid;
    if (nid < NN) srange[nid] = make_int2(s0 + st, s0 + st + val);
    ncnt[tid] = 0;                       // reuse as cursor
  }
  __syncthreads();

  for (int i = tid; i < cnt; i += 512) {
    int r = srec[i];
    int tl = r & 127;
    int p = atomicAdd(&ncnt[tl], 1);
    brec[s0 + nst[tl] + p] = r >> 7;     // final: grouped src ids
  }
}

#define UNPK(D_, U0_, U1_)                             \
  D_.x = __uint_as_float((U0_) << 16);                 \
  D_.y = __uint_as_float((U0_) & 0xffff0000u);         \
  D_.z = __uint_as_float((U1_) << 16);                 \
  D_.w = __uint_as_float((U1_) & 0xffff0000u);

#define ACC(AC_, E_, X_)                               \
  AC_.x = fmaf(E_, X_.x, AC_.x); AC_.y = fmaf(E_, X_.y, AC_.y); \
  AC_.z = fmaf(E_, X_.z, AC_.z); AC_.w = fmaf(E_, X_.w, AC_.w);

// One wave per node; 16 lanes per edge (4 heads x float4), 16 edges in flight
// (r10 proven body). All of h is bf16: xi unpacked once per node.
__global__ __launch_bounds__(256) void node_k(const unsigned short* __restrict__ hb,
                                              const int* __restrict__ ssrc,
                                              const int2* __restrict__ srange,
                                              const float* __restrict__ att,
                                              const float* __restrict__ bias,
                                              float* __restrict__ out) {
  const int lane = threadIdx.x & 63;
  const int n  = blockIdx.x * 4 + (threadIdx.x >> 6);
  const int g  = lane >> 4;          // edge slot 0..3
  const int fo = (lane & 15) * 4;    // (head,feature-quad) offset within 64

  uint2 xiu = *reinterpret_cast<const uint2*>(hb + (size_t)n * 128 + fo);
  float4 xi;
  UNPK(xi, xiu.x, xiu.y);
  const float4 a = *reinterpret_cast<const float4*>(att + fo);
  const int2 se = srange[n];
  const int s = se.x, e = se.y;
  const unsigned short* __restrict__ hrp = hb + 64 + fo;

  float  den = 0.f;
  float4 acc = make_float4(0.f, 0.f, 0.f, 0.f);

  for (int i = s; i < e; i += 16) {
    uint2 p[4];
    bool  v[4];
#pragma unroll
    for (int u = 0; u < 4; ++u) {      // 4 independent gathers in flight
      int r = i + u * 4 + g;
      v[u] = r < e;
      int j = ssrc[v[u] ? r : s];
      p[u] = *reinterpret_cast<const uint2*>(hrp + (size_t)j * 128);
    }
#pragma unroll
    for (int u = 0; u < 4; ++u) {
      float4 x;
      UNPK(x, p[u].x, p[u].y);
      float4 z;
      z.x = xi.x + x.x; z.y = xi.y + x.y; z.z = xi.z + x.z; z.w = xi.w + x.w;
      z.x = fmaxf(z.x, 0.2f * z.x); z.y = fmaxf(z.y, 0.2f * z.y);
      z.z = fmaxf(z.z, 0.2f * z.z); z.w = fmaxf(z.w, 0.2f * z.w);
      float t = z.x * a.x;
      t = fmaf(z.y, a.y, t); t = fmaf(z.z, a.z, t); t = fmaf(z.w, a.w, t);
      t += __shfl_xor(t, 1); t += __shfl_xor(t, 2);   // per-head dot (4 lanes)
      float ex = v[u] ? __expf(t) : 0.f;              // |score| << 88: no max-shift
      den += ex;
      ACC(acc, ex, x);
    }
  }

  // reduce across the 4 edge slots
#pragma unroll
  for (int m = 16; m <= 32; m <<= 1) {
    den   += __shfl_xor(den, m);
    acc.x += __shfl_xor(acc.x, m);
    acc.y += __shfl_xor(acc.y, m);
    acc.z += __shfl_xor(acc.z, m);
    acc.w += __shfl_xor(acc.w, m);
  }

  if (g == 0) {
    float inv = (e > s) ? 1.f / den : 0.f;   // deg==0 -> bias only
    float4 b4 = *reinterpret_cast<const float4*>(bias + fo);
    float4 r;
    r.x = fmaf(acc.x, inv, b4.x);
    r.y = fmaf(acc.y, inv, b4.y);
    r.z = fmaf(acc.z, inv, b4.z);
    r.w = fmaf(acc.w, inv, b4.w);
    *reinterpret_cast<float4*>(out + (size_t)n * 64 + fo) = r;
  }
}

extern "C" void kernel_launch(void* const* d_in, const int* in_sizes, int n_in,
                              void* d_out, int out_size, void* d_ws, size_t ws_size,
                              hipStream_t stream) {
  const float* feat = (const float*)d_in[0];
  const int*   edge = (const int*)d_in[1];
  const float* wl   = (const float*)d_in[2];
  const float* wr   = (const float*)d_in[3];
  const float* att  = (const float*)d_in[4];
  const float* bias = (const float*)d_in[5];
  float* out = (float*)d_out;

  // workspace layout (~35 MB)
  unsigned short* hb = (unsigned short*)d_ws;            // NN*128 bf16
  int*   brec     = (int*)(hb + (size_t)NN * 128);       // NB*BCAP (padded buckets)
  int*   bcursor  = brec + (size_t)NB * BCAP;            // NB*16 (padded, 1/line)
  int2*  srange   = (int2*)(bcursor + NB * 16);          // NN int2
  unsigned short* wt = (unsigned short*)(srange + NN);   // 16384 bf16

  const int nchunk = (NE + CHUNK - 1) / CHUNK;           // 391
  wprep_k<<<64, 256, 0, stream>>>(wl, wr, wt, bcursor);
  gemm_mfma<<<(NN + 63) / 64, 256, 0, stream>>>(feat, wt, hb);
  bscatter_k<<<nchunk, 512, 0, stream>>>(edge, bcursor, brec);
  bsort_k<<<NB, 512, 0, stream>>>(brec, bcursor, srange);
  node_k<<<NN / 4, 256, 0, stream>>>(hb, brec, srange, att, bias, out);
}

// Round 14
// 223.089 us; speedup vs baseline: 1.0250x; 1.0250x over previous
//
#include <hip/hip_runtime.h>

#define NN 100000
#define NE 1600000
#define NB 782          // ceil(NN/128) coarse buckets, 128 nodes each
#define CHUNK 4096
#define BCAP 2560       // padded bucket capacity (mean 2048, sigma ~45 -> 11 sigma)
#define LDP 136         // LDS row pitch in bf16 (128 + 8 pad -> 272B, 2-way free)

typedef __attribute__((ext_vector_type(8))) short bf16x8;
typedef __attribute__((ext_vector_type(4))) float f32x4;

static __device__ __forceinline__ unsigned short f2bf(float f) {
  unsigned int u = __float_as_uint(f);
  u += 0x7fff + ((u >> 16) & 1);       // round-to-nearest-even
  return (unsigned short)(u >> 16);
}

// One-time: wt[c][k] = bf16(W[k][c]) (c<64 -> W_l, c>=64 -> W_r) + bucket cursor init
__global__ void wprep_k(const float* __restrict__ wl, const float* __restrict__ wr,
                        unsigned short* __restrict__ wt, int* __restrict__ bcursor) {
  int i = blockIdx.x * 256 + threadIdx.x;     // 16384
  int c = i >> 7, k = i & 127;
  float v = (c < 64) ? wl[k * 64 + c] : wr[k * 64 + (c - 64)];
  wt[i] = f2bf(v);
  if (i < NB) bcursor[i * 16] = i * BCAP;     // padded-region base
}

// MFMA bf16 GEMM, 128-row tiles (r12 proven: LDS A-staging, B direct from
// the 16 KB L1/L2-resident wt table). hl f32, hrb bf16.
__global__ __launch_bounds__(256) void gemm_mfma(const float* __restrict__ feat,
                                                 const unsigned short* __restrict__ wt,
                                                 float* __restrict__ hl,
                                                 unsigned short* __restrict__ hrb) {
  __shared__ unsigned short ldsA[128][LDP];   // feat tile, bf16 [row][k]
  const int tid = threadIdx.x;
  const int row0 = blockIdx.x * 128;

  for (int it = 0; it < 16; ++it) {
    int r = it * 8 + (tid >> 5);
    int gr = row0 + r;
    int k4 = (tid & 31) * 4;
    float4 v = make_float4(0.f, 0.f, 0.f, 0.f);
    if (gr < NN) v = *reinterpret_cast<const float4*>(&feat[(size_t)gr * 128 + k4]);
    union { unsigned short s[4]; uint2 u; } pk;
    pk.s[0] = f2bf(v.x); pk.s[1] = f2bf(v.y); pk.s[2] = f2bf(v.z); pk.s[3] = f2bf(v.w);
    *reinterpret_cast<uint2*>(&ldsA[r][k4]) = pk.u;
  }
  __syncthreads();

  const int w  = tid >> 6;
  const int ln = tid & 63;
  const int lr = ln & 15;
  const int kb = (ln >> 4) * 8;

  f32x4 acc[2][8];
#pragma unroll
  for (int mt = 0; mt < 2; ++mt)
#pragma unroll
    for (int nt = 0; nt < 8; ++nt) acc[mt][nt] = (f32x4){0.f, 0.f, 0.f, 0.f};

#pragma unroll
  for (int t = 0; t < 4; ++t) {
    const int ko = t * 32 + kb;
    bf16x8 af0 = *reinterpret_cast<const bf16x8*>(&ldsA[w * 32 + lr][ko]);
    bf16x8 af1 = *reinterpret_cast<const bf16x8*>(&ldsA[w * 32 + 16 + lr][ko]);
    bf16x8 bfr[8];
#pragma unroll
    for (int nt = 0; nt < 8; ++nt)
      bfr[nt] = *reinterpret_cast<const bf16x8*>(&wt[(size_t)(nt * 16 + lr) * 128 + ko]);
#pragma unroll
    for (int nt = 0; nt < 8; ++nt) {
      acc[0][nt] = __builtin_amdgcn_mfma_f32_16x16x32_bf16(af0, bfr[nt], acc[0][nt], 0, 0, 0);
      acc[1][nt] = __builtin_amdgcn_mfma_f32_16x16x32_bf16(af1, bfr[nt], acc[1][nt], 0, 0, 0);
    }
  }

#pragma unroll
  for (int mt = 0; mt < 2; ++mt) {
    int rrel = w * 32 + mt * 16 + (ln >> 4) * 4;
#pragma unroll
    for (int q = 0; q < 4; ++q) {
      int gr = row0 + rrel + q;
      if (gr < NN) {
#pragma unroll
        for (int nt = 0; nt < 4; ++nt)       // cols 0..63 -> h_l (f32)
          hl[(size_t)gr * 64 + nt * 16 + lr] = acc[mt][nt][q];
#pragma unroll
        for (int nt = 4; nt < 8; ++nt)       // cols 64..127 -> h_r (bf16)
          hrb[(size_t)gr * 64 + (nt - 4) * 16 + lr] = f2bf(acc[mt][nt][q]);
      }
    }
  }
}

// Bucket-partition edges into fixed padded regions. 512 threads.
// rec = (src<<7)|tgt_local.
__global__ __launch_bounds__(512) void bscatter_k(const int* __restrict__ edge,
                                                  int* __restrict__ bcursor,
                                                  int* __restrict__ brec) {
  __shared__ int lcnt[NB];
  __shared__ int lstart[NB];
  __shared__ int gbase[NB];
  __shared__ int lcur[NB];
  __shared__ int srec[CHUNK];
  __shared__ unsigned short bid[CHUNK];
  __shared__ int sd[512];
  const int tid = threadIdx.x;
  const int base = blockIdx.x * CHUNK;
  const int lim = min(CHUNK, NE - base);

  for (int b = tid; b < NB; b += 512) { lcnt[b] = 0; lcur[b] = 0; }
  __syncthreads();
  for (int i = tid; i < lim; i += 512)
    atomicAdd(&lcnt[edge[NE + base + i] >> 7], 1);
  __syncthreads();

  int v[2]; int s = 0;
#pragma unroll
  for (int j = 0; j < 2; ++j) {
    int idx = tid * 2 + j;
    v[j] = (idx < NB) ? lcnt[idx] : 0;
    s += v[j];
  }
  sd[tid] = s;
  __syncthreads();
  for (int off = 1; off < 512; off <<= 1) {
    int t = (tid >= off) ? sd[tid - off] : 0;
    __syncthreads();
    sd[tid] += t;
    __syncthreads();
  }
  int run = sd[tid] - s;
#pragma unroll
  for (int j = 0; j < 2; ++j) {
    int idx = tid * 2 + j;
    if (idx < NB) lstart[idx] = run;
    run += v[j];
  }
  __syncthreads();

  for (int b = tid; b < NB; b += 512)
    if (lcnt[b] > 0) gbase[b] = atomicAdd(&bcursor[b * 16], lcnt[b]);
  __syncthreads();

  for (int i = tid; i < lim; i += 512) {
    int tg = edge[NE + base + i];
    int sr = edge[base + i];
    int b = tg >> 7;
    int r = atomicAdd(&lcur[b], 1);
    int slot = lstart[b] + r;
    srec[slot] = (sr << 7) | (tg & 127);
    bid[slot] = (unsigned short)b;
  }
  __syncthreads();

  for (int i = tid; i < lim; i += 512) {
    int b = bid[i];
    brec[gbase[b] + i - lstart[b]] = srec[i];
  }
}

// Node-level sort within each padded bucket; emits absolute (start,end) per node.
__global__ __launch_bounds__(512) void bsort_k(int* __restrict__ brec,
                                               const int* __restrict__ bcursor,
                                               int2* __restrict__ srange) {
  __shared__ int srec[BCAP];
  __shared__ int ncnt[128];
  __shared__ int nst[128];
  __shared__ int sd2[128];
  const int tid = threadIdx.x;
  const int b = blockIdx.x;
  const int s0 = b * BCAP;
  const int cnt = bcursor[b * 16] - s0;

  if (tid < 128) ncnt[tid] = 0;
  __syncthreads();
  for (int i = tid; i < cnt; i += 512) {
    int r = brec[s0 + i];
    srec[i] = r;
    atomicAdd(&ncnt[r & 127], 1);
  }
  __syncthreads();

  int val = (tid < 128) ? ncnt[tid] : 0;
  if (tid < 128) sd2[tid] = val;
  __syncthreads();
  for (int off = 1; off < 128; off <<= 1) {
    int t = 0;
    if (tid < 128 && tid >= off) t = sd2[tid - off];
    __syncthreads();
    if (tid < 128) sd2[tid] += t;
    __syncthreads();
  }
  if (tid < 128) {
    int st = sd2[tid] - val;
    nst[tid] = st;
    int nid = (b << 7) + tid;
    if (nid < NN) srange[nid] = make_int2(s0 + st, s0 + st + val);
    ncnt[tid] = 0;                       // reuse as cursor
  }
  __syncthreads();

  for (int i = tid; i < cnt; i += 512) {
    int r = srec[i];
    int tl = r & 127;
    int p = atomicAdd(&ncnt[tl], 1);
    brec[s0 + nst[tl] + p] = r >> 7;     // final: grouped src ids
  }
}

#define UNPK(D_, U0_, U1_)                             \
  D_.x = __uint_as_float((U0_) << 16);                 \
  D_.y = __uint_as_float((U0_) & 0xffff0000u);         \
  D_.z = __uint_as_float((U1_) << 16);                 \
  D_.w = __uint_as_float((U1_) & 0xffff0000u);

#define ACC(AC_, E_, X_)                               \
  AC_.x = fmaf(E_, X_.x, AC_.x); AC_.y = fmaf(E_, X_.y, AC_.y); \
  AC_.z = fmaf(E_, X_.z, AC_.z); AC_.w = fmaf(E_, X_.w, AC_.w);

// One wave per node; 16 lanes per edge (4 heads x float4), 16 edges in flight
// (r10/r12 proven body). base = node offset (grid split in two for profile
// attribution: each half ~27us, letting gemm/bscatter/bsort surface in top-5).
__global__ __launch_bounds__(256) void node_k(const float* __restrict__ hl,
                                              const unsigned short* __restrict__ hrb,
                                              const int* __restrict__ ssrc,
                                              const int2* __restrict__ srange,
                                              const float* __restrict__ att,
                                              const float* __restrict__ bias,
                                              float* __restrict__ out,
                                              int base) {
  const int lane = threadIdx.x & 63;
  const int n  = base + blockIdx.x * 4 + (threadIdx.x >> 6);
  const int g  = lane >> 4;          // edge slot 0..3
  const int fo = (lane & 15) * 4;    // (head,feature-quad) offset within 64

  const float4 xi = *reinterpret_cast<const float4*>(hl + (size_t)n * 64 + fo);
  const float4 a  = *reinterpret_cast<const float4*>(att + fo);
  const int2 se = srange[n];
  const int s = se.x, e = se.y;
  const unsigned short* __restrict__ hrp = hrb + fo;

  float  den = 0.f;
  float4 acc = make_float4(0.f, 0.f, 0.f, 0.f);

  for (int i = s; i < e; i += 16) {
    uint2 p[4];
    bool  v[4];
#pragma unroll
    for (int u = 0; u < 4; ++u) {      // 4 independent gathers in flight
      int r = i + u * 4 + g;
      v[u] = r < e;
      int j = ssrc[v[u] ? r : s];
      p[u] = *reinterpret_cast<const uint2*>(hrp + (size_t)j * 64);
    }
#pragma unroll
    for (int u = 0; u < 4; ++u) {
      float4 x;
      UNPK(x, p[u].x, p[u].y);
      float4 z;
      z.x = xi.x + x.x; z.y = xi.y + x.y; z.z = xi.z + x.z; z.w = xi.w + x.w;
      z.x = fmaxf(z.x, 0.2f * z.x); z.y = fmaxf(z.y, 0.2f * z.y);
      z.z = fmaxf(z.z, 0.2f * z.z); z.w = fmaxf(z.w, 0.2f * z.w);
      float t = z.x * a.x;
      t = fmaf(z.y, a.y, t); t = fmaf(z.z, a.z, t); t = fmaf(z.w, a.w, t);
      t += __shfl_xor(t, 1); t += __shfl_xor(t, 2);   // per-head dot (4 lanes)
      float ex = v[u] ? __expf(t) : 0.f;              // |score| << 88: no max-shift
      den += ex;
      ACC(acc, ex, x);
    }
  }

  // reduce across the 4 edge slots
#pragma unroll
  for (int m = 16; m <= 32; m <<= 1) {
    den   += __shfl_xor(den, m);
    acc.x += __shfl_xor(acc.x, m);
    acc.y += __shfl_xor(acc.y, m);
    acc.z += __shfl_xor(acc.z, m);
    acc.w += __shfl_xor(acc.w, m);
  }

  if (g == 0) {
    float inv = (e > s) ? 1.f / den : 0.f;   // deg==0 -> bias only
    float4 b4 = *reinterpret_cast<const float4*>(bias + fo);
    float4 r;
    r.x = fmaf(acc.x, inv, b4.x);
    r.y = fmaf(acc.y, inv, b4.y);
    r.z = fmaf(acc.z, inv, b4.z);
    r.w = fmaf(acc.w, inv, b4.w);
    *reinterpret_cast<float4*>(out + (size_t)n * 64 + fo) = r;
  }
}

extern "C" void kernel_launch(void* const* d_in, const int* in_sizes, int n_in,
                              void* d_out, int out_size, void* d_ws, size_t ws_size,
                              hipStream_t stream) {
  const float* feat = (const float*)d_in[0];
  const int*   edge = (const int*)d_in[1];
  const float* wl   = (const float*)d_in[2];
  const float* wr   = (const float*)d_in[3];
  const float* att  = (const float*)d_in[4];
  const float* bias = (const float*)d_in[5];
  float* out = (float*)d_out;

  // workspace layout (~47.5 MB)
  float* hl       = (float*)d_ws;                        // NN*64 f32
  unsigned short* hrb = (unsigned short*)(hl + (size_t)NN * 64);  // NN*64 bf16
  int*   brec     = (int*)(hrb + (size_t)NN * 64);       // NB*BCAP (padded buckets)
  int*   bcursor  = brec + (size_t)NB * BCAP;            // NB*16 (padded, 1/line)
  int2*  srange   = (int2*)(bcursor + NB * 16);          // NN int2
  unsigned short* wt = (unsigned short*)(srange + NN);   // 16384 bf16

  const int nchunk = (NE + CHUNK - 1) / CHUNK;           // 391
  wprep_k<<<64, 256, 0, stream>>>(wl, wr, wt, bcursor);
  gemm_mfma<<<(NN + 127) / 128, 256, 0, stream>>>(feat, wt, hl, hrb);
  bscatter_k<<<nchunk, 512, 0, stream>>>(edge, bcursor, brec);
  bsort_k<<<NB, 512, 0, stream>>>(brec, bcursor, srange);
  node_k<<<12500, 256, 0, stream>>>(hl, hrb, brec, srange, att, bias, out, 0);
  node_k<<<12500, 256, 0, stream>>>(hl, hrb, brec, srange, att, bias, out, 50000);
}